// Round 4
// baseline (193.413 us; speedup 1.0000x reference)
//
#include <hip/hip_runtime.h>
#include <cstdint>
#include <cstddef>

typedef unsigned short u16;
typedef __bf16 bf16x8 __attribute__((ext_vector_type(8)));
typedef float    f32x4 __attribute__((ext_vector_type(4)));
typedef unsigned int u32x4 __attribute__((ext_vector_type(4)));

// ---------- problem constants ----------
constexpr int BB   = 16;
constexpr int NN   = 2048;
constexpr int SS   = 512;
constexpr int DD   = 384;   // D1 = D2 = 384
constexpr int CIN  = 768;   // D1+D2
constexpr int HID  = 768;
constexpr int OUTC = 384;
constexpr int MROWS = BB * NN; // 32768
constexpr float KNN_EPS = 1.1920929e-07f; // finfo(f32).eps
constexpr float BN_EPS  = 1e-5f;

// ---------- workspace layout (bytes) ----------
constexpr size_t OFF_W0B  = 0;                              // 768*768 bf16
constexpr size_t OFF_W1B  = OFF_W0B  + (size_t)HID*CIN*2;   // 384*768 bf16
constexpr size_t OFF_IDX  = OFF_W1B  + (size_t)OUTC*HID*2;  // MROWS*5 int
constexpr size_t OFF_WGT  = OFF_IDX  + (size_t)MROWS*5*4;
constexpr size_t OFF_SUM1 = OFF_WGT  + (size_t)MROWS*5*4;   // 768*2 f32
constexpr size_t OFF_SUM2 = OFF_SUM1 + (size_t)HID*2*4;     // 384*2 f32
constexpr size_t OFF_COEF1= OFF_SUM2 + (size_t)OUTC*2*4;    // 768*2 f32
constexpr size_t OFF_COEF2= OFF_COEF1+ (size_t)HID*2*4;     // 384*2 f32
constexpr size_t OFF_XCAT = OFF_COEF2+ (size_t)OUTC*2*4;    // MROWS*768 bf16
constexpr size_t OFF_H1   = OFF_XCAT + (size_t)MROWS*CIN*2; // MROWS*768 bf16

// ---------- helpers ----------
__device__ inline float bf2f(u16 u){ unsigned int i = ((unsigned int)u)<<16; float f; __builtin_memcpy(&f,&i,4); return f; }
__device__ inline u16 f2bf(float f){ unsigned int x; __builtin_memcpy(&x,&f,4);
  unsigned int r = (x + 0x7fffu + ((x>>16)&1u)) >> 16; return (u16)r; }

__device__ inline void async16(const void* g, void* l){
  __builtin_amdgcn_global_load_lds((const __attribute__((address_space(1))) void*)g,
                                   (__attribute__((address_space(3))) void*)l, 16, 0, 0);
}

// ---------- W f32 -> bf16 ----------
__global__ void cvtw_kernel(const float* __restrict__ W0, const float* __restrict__ W1,
                            u16* __restrict__ W0b, u16* __restrict__ W1b){
  int t = blockIdx.x*256 + threadIdx.x;
  if (t < HID*CIN)  W0b[t] = f2bf(W0[t]);
  if (t < OUTC*HID) W1b[t] = f2bf(W1[t]);
}

// ---------- KNN: one wave per query ----------
__global__ __launch_bounds__(256) void knn_kernel(const float* __restrict__ xyz1,
                                                  const float* __restrict__ xyz2,
                                                  const int* __restrict__ elens,
                                                  int* __restrict__ idxO, float* __restrict__ wO){
  __shared__ f32x4 sp[SS];
  const int tid = threadIdx.x;
  const int wv = tid >> 6, lane = tid & 63;
  const int wg = blockIdx.x*4 + wv;       // global wave id = query id
  const int b = wg >> 11;                 // 2048 queries per batch
  const int n = wg & (NN-1);
  for (int s = tid; s < SS; s += 256){
    float x = xyz2[((size_t)b*SS + s)*3 + 0];
    float y = xyz2[((size_t)b*SS + s)*3 + 1];
    float z = xyz2[((size_t)b*SS + s)*3 + 2];
    f32x4 v; v[0]=x; v[1]=y; v[2]=z; v[3]=x*x+y*y+z*z;
    sp[s]=v;
  }
  __syncthreads();
  const size_t qoff = ((size_t)b*NN + n)*3;
  const float qx = xyz1[qoff+0], qy = xyz1[qoff+1], qz = xyz1[qoff+2];
  const float qq = qx*qx + qy*qy + qz*qz;
  const int Sl = elens[b];

  float d0=1e30f,d1=1e30f,d2v=1e30f,d3=1e30f,d4=1e30f;
  int   i0=0,i1=0,i2=0,i3=0,i4=0;
  #pragma unroll
  for (int j=0;j<8;j++){
    const int s = lane + j*64;
    f32x4 v = sp[s];
    float d = (s < Sl) ? (qq + v[3] - 2.f*(qx*v[0] + qy*v[1] + qz*v[2])) : 1e30f;
    bool lt4=d<d4, lt3=d<d3, lt2=d<d2v, lt1=d<d1, lt0=d<d0;
    float nd4 = lt3 ? d3 : (lt4 ? d : d4); int ni4 = lt3 ? i3 : (lt4 ? s : i4);
    float nd3 = lt2 ? d2v: (lt3 ? d : d3); int ni3 = lt2 ? i2 : (lt3 ? s : i3);
    float nd2 = lt1 ? d1 : (lt2 ? d : d2v);int ni2 = lt1 ? i1 : (lt2 ? s : i2);
    float nd1 = lt0 ? d0 : (lt1 ? d : d1); int ni1 = lt0 ? i0 : (lt1 ? s : i1);
    float nd0 = lt0 ? d  : d0;             int ni0 = lt0 ? s  : i0;
    d4=nd4;i4=ni4; d3=nd3;i3=ni3; d2v=nd2;i2=ni2; d1=nd1;i1=ni1; d0=nd0;i0=ni0;
  }
  float outd[5]; int outi[5];
  #pragma unroll
  for (int r=0;r<5;r++){
    float bd = d0; int bs = i0;
    #pragma unroll
    for (int m=1;m<64;m<<=1){
      float od = __shfl_xor(bd, m, 64);
      int   os = __shfl_xor(bs, m, 64);
      if (od < bd || (od == bd && os < bs)){ bd = od; bs = os; }
    }
    outd[r]=bd; outi[r]=bs;
    if (d0 == bd && i0 == bs){ d0=d1;i0=i1; d1=d2v;i1=i2; d2v=d3;i2=i3; d3=d4;i3=i4; d4=1e30f;i4=0; }
  }
  if (lane == 0){
    float r0=1.f/(outd[0]+KNN_EPS), r1=1.f/(outd[1]+KNN_EPS), r2=1.f/(outd[2]+KNN_EPS),
          r3=1.f/(outd[3]+KNN_EPS), r4=1.f/(outd[4]+KNN_EPS);
    float inv = 1.f/(r0+r1+r2+r3+r4);
    size_t base = (size_t)wg*5;
    idxO[base+0]=outi[0]; idxO[base+1]=outi[1]; idxO[base+2]=outi[2]; idxO[base+3]=outi[3]; idxO[base+4]=outi[4];
    wO[base+0]=r0*inv; wO[base+1]=r1*inv; wO[base+2]=r2*inv; wO[base+3]=r3*inv; wO[base+4]=r4*inv;
  }
}

// ---------- build xcat = [points1 | interp] in bf16 ----------
__global__ __launch_bounds__(384) void xcat_kernel(const float* __restrict__ p1,
                                                   const float* __restrict__ p2,
                                                   const int* __restrict__ idx,
                                                   const float* __restrict__ wgt,
                                                   u16* __restrict__ xcat){
  const int c = threadIdx.x;
  const int rowbase = blockIdx.x*8;
  for (int i=0;i<8;i++){
    const int row = rowbase + i;
    const int b = row >> 11;
    float v1 = p1[(size_t)row*DD + c];
    xcat[(size_t)row*CIN + c] = f2bf(v1);
    float acc = 0.f;
    size_t ib = (size_t)row*5;
    #pragma unroll
    for (int k=0;k<5;k++){
      int id = idx[ib+k]; float w = wgt[ib+k];
      acc += w * p2[((size_t)b*SS + id)*DD + c];
    }
    xcat[(size_t)row*CIN + DD + c] = f2bf(acc);
  }
}

// ---------- bf16 GEMM: dist-2 prefetch ring, counted vmcnt, swizzled LDS ----------
// C[M][NC] = A[M][K] * Bw[NC][K]^T. Swizzle: chunk ch holds global col-block
// c8 = (ch&3)^((ch>>3)&3); read at r*32 + ((l16 ^ ((l15>>1)&3))<<3). This keeps
// global 64B-coalescing AND gives 2-way-max LDS banking (free).
// FUSE_A: A staged via regs (dbuf) with relu(a*x+b) applied; B async triple-buf.
template<bool OUT_BF16, bool FUSE_A, int GX, int K>
__global__ __launch_bounds__(256) void gemm_kernel(const u16* __restrict__ A,
                                                   const u16* __restrict__ Bw,
                                                   void* __restrict__ Cout,
                                                   const int* __restrict__ plen,
                                                   float* __restrict__ sums,
                                                   const float* __restrict__ cf){
  constexpr int NC = GX*128;
  constexpr int NSTEP = K/32;
  constexpr int NWG = GX*256;     // (MROWS/128) * GX
  constexpr int CPX = NWG/8;
  constexpr int NAB = FUSE_A ? 2 : 3;
  __shared__ u16 As[NAB][128*32];
  __shared__ u16 Bs[3][128*32];
  const int tid  = threadIdx.x;
  const int lane = tid & 63, wv = tid >> 6;
  const int wr = wv >> 1, wc = wv & 1;
  const int l15 = lane & 15, l16 = lane >> 4;
  const int sw  = (l15 >> 1) & 3;          // read-side swizzle selector

  // T1: chunked XCD swizzle
  const int logical = (blockIdx.x & 7)*CPX + (blockIdx.x >> 3);
  const int bn = logical % GX, bm = logical / GX;

  // staging geometry: 512 chunks of 16B per tile, 2 chunks/thread, swizzled c8
  int c8S[2], ldso[2];
  const u16* Ab[2]; const u16* Bb[2];
  #pragma unroll
  for (int j=0;j<2;j++){
    int ch = j*256 + wv*64 + lane;
    int row = ch >> 2;
    int c8 = (ch & 3) ^ ((ch >> 3) & 3);
    c8S[j] = c8;
    ldso[j] = (j*256 + wv*64)*16;          // wave-uniform LDS byte base
    Ab[j] = A  + (size_t)(bm*128 + row)*K + c8*8;
    Bb[j] = Bw + (size_t)(bn*128 + row)*K + c8*8;
  }

  auto stageA = [&](int nb, int kt){
    #pragma unroll
    for (int j=0;j<2;j++) async16(Ab[j] + kt*32, (char*)&As[nb][0] + ldso[j]);
  };
  auto stageB = [&](int nb, int kt){
    #pragma unroll
    for (int j=0;j<2;j++) async16(Bb[j] + kt*32, (char*)&Bs[nb][0] + ldso[j]);
  };
  u32x4 hv0, hv1;
  auto loadA = [&](int kt){
    hv0 = *reinterpret_cast<const u32x4*>(Ab[0] + kt*32);
    hv1 = *reinterpret_cast<const u32x4*>(Ab[1] + kt*32);
  };
  auto bnwrite = [&](int nb, int kt){
    #pragma unroll
    for (int j=0;j<2;j++){
      const int k0 = kt*32 + c8S[j]*8;
      float av[8], bv[8];
      *reinterpret_cast<f32x4*>(av)   = *reinterpret_cast<const f32x4*>(cf + k0);
      *reinterpret_cast<f32x4*>(av+4) = *reinterpret_cast<const f32x4*>(cf + k0 + 4);
      *reinterpret_cast<f32x4*>(bv)   = *reinterpret_cast<const f32x4*>(cf + K + k0);
      *reinterpret_cast<f32x4*>(bv+4) = *reinterpret_cast<const f32x4*>(cf + K + k0 + 4);
      u32x4 v = j ? hv1 : hv0; u32x4 o;
      #pragma unroll
      for (int q=0;q<4;q++){
        float lo = bf2f((u16)(v[q] & 0xffffu));
        float hi = bf2f((u16)(v[q] >> 16));
        lo = fmaxf(lo*av[2*q]   + bv[2*q],   0.f);
        hi = fmaxf(hi*av[2*q+1] + bv[2*q+1], 0.f);
        o[q] = (unsigned int)f2bf(lo) | ((unsigned int)f2bf(hi) << 16);
      }
      *reinterpret_cast<u32x4*>((char*)&As[nb][0] + ldso[j] + lane*16) = o;
    }
  };

  f32x4 acc[4][4] = {};

  // ---- prologue: tiles 0,1 in flight ----
  if constexpr (FUSE_A){
    loadA(0);
    __builtin_amdgcn_sched_barrier(0);
    stageB(0, 0); stageB(1, 1);
    bnwrite(0, 0);                          // compiler waits vmcnt for hv here
    asm volatile("s_waitcnt vmcnt(2) lgkmcnt(0)" ::: "memory");  // B0 landed, B1 in flight
    __builtin_amdgcn_s_barrier();
  } else {
    stageA(0, 0); stageB(0, 0);
    stageA(1, 1); stageB(1, 1);
    asm volatile("s_waitcnt vmcnt(4) lgkmcnt(0)" ::: "memory");  // tile0 landed
    __builtin_amdgcn_s_barrier();
  }

  int rb = 0, wb = 2;                        // read / write ring positions (B; A too if !FUSE)
  for (int kt=0; kt<NSTEP; ++kt){
    const bool pf1 = (kt+1 < NSTEP), pf2 = (kt+2 < NSTEP);
    if constexpr (FUSE_A){
      if (pf1) loadA(kt+1);
      __builtin_amdgcn_sched_barrier(0);     // pin: reg-loads issue before stageB
      if (pf2) stageB(wb, kt+2);
    } else {
      if (pf2){ stageA(wb, kt+2); stageB(wb, kt+2); }
    }

    bf16x8 af[4], bfr[4];
    const int aslot = FUSE_A ? (kt & 1) : rb;
    #pragma unroll
    for (int m=0;m<4;m++){
      int r = wr*64 + m*16 + l15;
      af[m] = *reinterpret_cast<const bf16x8*>(&As[aslot][r*32 + ((l16 ^ sw) << 3)]);
    }
    #pragma unroll
    for (int n=0;n<4;n++){
      int c = wc*64 + n*16 + l15;
      bfr[n] = *reinterpret_cast<const bf16x8*>(&Bs[rb][c*32 + ((l16 ^ sw) << 3)]);
    }
    #pragma unroll
    for (int m=0;m<4;m++)
      #pragma unroll
      for (int n=0;n<4;n++)
        acc[m][n] = __builtin_amdgcn_mfma_f32_16x16x32_bf16(af[m], bfr[n], acc[m][n], 0, 0, 0);

    if constexpr (FUSE_A){ if (pf1) bnwrite((kt+1)&1, kt+1); }

    if (pf1){
      if (pf2){
        if constexpr (FUSE_A) asm volatile("s_waitcnt vmcnt(2) lgkmcnt(0)" ::: "memory");
        else                  asm volatile("s_waitcnt vmcnt(4) lgkmcnt(0)" ::: "memory");
      } else {
        asm volatile("s_waitcnt vmcnt(0) lgkmcnt(0)" ::: "memory");
      }
      __builtin_amdgcn_s_barrier();
    }
    rb = (rb==2) ? 0 : rb+1;
    wb = (wb==2) ? 0 : wb+1;
  }

  // ---- C write ----
  #pragma unroll
  for (int m=0;m<4;m++){
    int r0 = bm*128 + wr*64 + m*16 + l16*4;
    #pragma unroll
    for (int n=0;n<4;n++){
      int c = bn*128 + wc*64 + n*16 + l15;
      #pragma unroll
      for (int r=0;r<4;r++){
        size_t off = (size_t)(r0+r)*NC + c;
        if (OUT_BF16) ((u16*)Cout)[off] = f2bf(acc[m][n][r]);
        else          ((float*)Cout)[off] = acc[m][n][r];
      }
    }
  }

  // ---- fused masked stats: per-column sum / sumsq ----
  const int pl = plen[bm >> 4];                       // 16 row-tiles per batch
  const int rbase = (bm & 15)*128 + wr*64 + l16*4;    // row within batch
  float cs[4] = {0.f,0.f,0.f,0.f}, cs2[4] = {0.f,0.f,0.f,0.f};
  #pragma unroll
  for (int m=0;m<4;m++){
    #pragma unroll
    for (int r=0;r<4;r++){
      if (rbase + m*16 + r < pl){
        #pragma unroll
        for (int n=0;n<4;n++){
          float v = acc[m][n][r];
          cs[n] += v; cs2[n] += v*v;
        }
      }
    }
  }
  #pragma unroll
  for (int n=0;n<4;n++){
    cs[n]  += __shfl_xor(cs[n], 16, 64);  cs[n]  += __shfl_xor(cs[n], 32, 64);
    cs2[n] += __shfl_xor(cs2[n], 16, 64); cs2[n] += __shfl_xor(cs2[n], 32, 64);
  }
  float* lsum = (float*)&As[0][0];   // [0:128)=sum, [128:256)=sumsq (safe: see barrier analysis)
  lsum[tid] = 0.f;
  __syncthreads();
  if (l16 == 0){
    #pragma unroll
    for (int n=0;n<4;n++){
      int col = wc*64 + n*16 + l15;
      atomicAdd(&lsum[col], cs[n]);
      atomicAdd(&lsum[128 + col], cs2[n]);
    }
  }
  __syncthreads();
  if (tid < 128)       atomicAdd(&sums[bn*128 + tid], lsum[tid]);
  else                 atomicAdd(&sums[NC + bn*128 + (tid-128)], lsum[tid]);
}

// ---------- fold BN params: a = g*rsqrt(var+eps), c = b - mean*a ----------
__global__ void coef_kernel(const float* __restrict__ sums, const int* __restrict__ plen,
                            const float* __restrict__ g, const float* __restrict__ bta,
                            float* __restrict__ coef, int C){
  int c = threadIdx.x;
  if (c >= C) return;
  float cnt = 0.f;
  for (int b=0;b<BB;b++) cnt += (float)plen[b];
  float mean = sums[c] / cnt;
  float var  = sums[C + c] / cnt - mean*mean;
  var = fmaxf(var, 0.f);
  float a = g[c] * rsqrtf(var + BN_EPS);
  coef[c] = a;
  coef[C + c] = bta[c] - mean*a;
}

// ---------- final in-place: y = relu(y*a + c) ----------
__global__ __launch_bounds__(256) void final_kernel(float* __restrict__ Y,
                                                    const float* __restrict__ coef){
  size_t t = (size_t)blockIdx.x*256 + threadIdx.x;
  size_t f = t*4;
  int c = (int)(f % (size_t)OUTC);
  f32x4 v = *reinterpret_cast<const f32x4*>(Y + f);
  #pragma unroll
  for (int j=0;j<4;j++)
    v[j] = fmaxf(v[j]*coef[c+j] + coef[OUTC+c+j], 0.f);
  *reinterpret_cast<f32x4*>(Y + f) = v;
}

extern "C" void kernel_launch(void* const* d_in, const int* in_sizes, int n_in,
                              void* d_out, int out_size, void* d_ws, size_t ws_size,
                              hipStream_t stream){
  (void)in_sizes; (void)n_in; (void)out_size; (void)ws_size;
  const float* xyz1 = (const float*)d_in[0];
  const float* xyz2 = (const float*)d_in[1];
  const float* p1   = (const float*)d_in[2];
  const float* p2   = (const float*)d_in[3];
  const int*   plen = (const int*)d_in[4];
  const int*   elen = (const int*)d_in[5];
  const float* W0   = (const float*)d_in[7];
  const float* g0   = (const float*)d_in[8];
  const float* b0   = (const float*)d_in[9];
  const float* W1   = (const float*)d_in[10];
  const float* g1   = (const float*)d_in[11];
  const float* b1   = (const float*)d_in[12];
  float* out = (float*)d_out;
  char*  ws  = (char*)d_ws;

  u16*   W0b  = (u16*)  (ws + OFF_W0B);
  u16*   W1b  = (u16*)  (ws + OFF_W1B);
  int*   idxb = (int*)  (ws + OFF_IDX);
  float* wgtb = (float*)(ws + OFF_WGT);
  float* sum1 = (float*)(ws + OFF_SUM1);
  float* sum2 = (float*)(ws + OFF_SUM2);
  float* coef1= (float*)(ws + OFF_COEF1);
  float* coef2= (float*)(ws + OFF_COEF2);
  u16*   xcat = (u16*)  (ws + OFF_XCAT);
  u16*   h1   = (u16*)  (ws + OFF_H1);

  // zero the stats accumulators (atomics accumulate each launch)
  hipMemsetAsync(ws + OFF_SUM1, 0, (size_t)(HID*2 + OUTC*2)*4, stream);

  cvtw_kernel<<<(HID*CIN + 255)/256, 256, 0, stream>>>(W0, W1, W0b, W1b);
  knn_kernel<<<MROWS/4, 256, 0, stream>>>(xyz1, xyz2, elen, idxb, wgtb);
  xcat_kernel<<<MROWS/8, 384, 0, stream>>>(p1, p2, idxb, wgtb, xcat);

  // GEMM1: h1 = xcat @ W0^T  (bf16 out, stats fused)
  gemm_kernel<true, false, 6, CIN><<<6*256, 256, 0, stream>>>(xcat, W0b, h1, plen, sum1, nullptr);
  coef_kernel<<<1, HID, 0, stream>>>(sum1, plen, g0, b0, coef1, HID);

  // GEMM2: out = relu(bn(h1)) @ W1^T  (BN+ReLU fused into A-staging, f32 out, stats fused)
  gemm_kernel<false, true, 3, HID><<<3*256, 256, 0, stream>>>(h1, W1b, out, plen, sum2, coef1);
  coef_kernel<<<1, OUTC, 0, stream>>>(sum2, plen, g1, b1, coef2, OUTC);
  final_kernel<<<(size_t)MROWS*OUTC/4/256, 256, 0, stream>>>(out, coef2);
}